// Round 12
// baseline (235.561 us; speedup 1.0000x reference)
//
#include <hip/hip_runtime.h>
#include <stdint.h>

#define B_ 16
#define T_ 4096
#define C_ 64
#define H_ 128
#define BQ 128
#define BK 128

typedef _Float16 f16;
typedef __attribute__((ext_vector_type(8))) _Float16 half8;   // 4 VGPRs (16x16x32 A/B)
typedef __attribute__((ext_vector_type(4))) _Float16 half4;   // 2 VGPRs
typedef __attribute__((ext_vector_type(2))) _Float16 half2v;  // 1 VGPR
typedef __attribute__((ext_vector_type(4))) float   floatx4;  // MFMA C/D frag

__device__ __forceinline__ f16 f2h(float f) { return (f16)f; }

__device__ __forceinline__ float fexp2(float x) {
#if __has_builtin(__builtin_amdgcn_exp2f)
    return __builtin_amdgcn_exp2f(x);
#else
    return exp2f(x);
#endif
}

// packed f32x2 -> f16x2 (single v_cvt_pkrtz_f16_f32)
__device__ __forceinline__ half2v pkrtz(float a, float b) {
    return __builtin_bit_cast(half2v, __builtin_amdgcn_cvt_pkrtz(a, b));
}

// async global->LDS, 16 B per lane, dest = wave-uniform base + lane*16
__device__ __forceinline__ void async_cp16(const void* g, void* l) {
    __builtin_amdgcn_global_load_lds(
        (const __attribute__((address_space(1))) unsigned int*)g,
        (__attribute__((address_space(3))) unsigned int*)l, 16, 0, 0);
}

// q is pre-scaled by scale*log2(e) at projection time (attn does exp2(S) raw)
#define QSCALE 0.18033688011112042f   // 0.125 * log2(e)

// ---------------------------------------------------------------------------
// W prep: Wk/Wq/Wv fp32 [C][H] -> f16 W^T [m][H][C], done ONCE.
// Grid (3 m, 16 h-groups) = 48 blocks.
// ---------------------------------------------------------------------------
__global__ __launch_bounds__(256) void wprep_kernel(
    const float* __restrict__ Wk, const float* __restrict__ Wq,
    const float* __restrict__ Wv, f16* __restrict__ wt)
{
    const int m  = blockIdx.x;
    const int hg = blockIdx.y;
    const float* W = (m == 0) ? Wk : (m == 1) ? Wq : Wv;
    f16* o = wt + m * (C_ * H_);
    #pragma unroll
    for (int it = 0; it < 2; ++it) {
        int idx = hg * 512 + it * 256 + threadIdx.x;  // idx = h*64 + c
        int h = idx >> 6, c = idx & 63;
        o[idx] = f2h(W[c * H_ + h]);                  // strided 4B reads, L2-resident
    }
}

// ---------------------------------------------------------------------------
// MFMA projections: q,k -> f16 [B][T][H]; v -> f16 vt[B][H][T'].
// vt's t-order is PERMUTED within each 64-t chunk so attn's PV operand is one
// contiguous 16-B granule per lane:
//   position p = 8g+u  holds  t-offset k = 32*g2 | 16*u2 | 8*g1 | 4*g0 | u1u0
// (g = granule 0..7, u = 0..7). Then granule g = 4*sp + quad is exactly the
// 8 k-values lane(quad) needs for PV tile-pair sp -> single b128 read.
// q (m==1) is multiplied by QSCALE before the f16 store.
// ---------------------------------------------------------------------------
#define QKS 132   // q/k scratch stride (f16)
#define VTS 72    // vt scratch stride (f16)

__global__ __launch_bounds__(256) void proj_kernel(
    const float* __restrict__ x, const f16* __restrict__ wt,
    f16* __restrict__ qo, f16* __restrict__ ko, f16* __restrict__ vto)
{
    __shared__ __align__(16) char smem[20480];
    f16* Sw  = (f16*)smem;                          // per-wave [16][QKS] transpose scratch
    f16* vtl = (f16*)smem;                          // [128 h][VTS]  18432 B (aliases Sw)

    const int tid  = threadIdx.x;
    const int wave = tid >> 6;
    const int lane = tid & 63;
    const int col  = lane & 15;
    const int quad = lane >> 4;
    const int b    = blockIdx.x >> 6;
    const int t0   = (blockIdx.x & 63) * 64;

    // A-fragments: x rows t0+wave*16+col, K=64 in 2 ks-steps (fp32 -> f16)
    half8 ax[2];
    {
        const float* xr = x + ((size_t)(b * T_ + t0 + wave * 16 + col)) * C_ + quad * 8;
        #pragma unroll
        for (int ks = 0; ks < 2; ++ks) {
            float4 a0 = *(const float4*)(xr + ks * 32);
            float4 a1 = *(const float4*)(xr + ks * 32 + 4);
            ax[ks] = half8{f2h(a0.x), f2h(a0.y), f2h(a0.z), f2h(a0.w),
                           f2h(a1.x), f2h(a1.y), f2h(a1.z), f2h(a1.w)};
        }
    }

    #pragma unroll
    for (int m = 0; m < 3; ++m) {
        const f16* Wm = wt + m * (C_ * H_);
        const float sc = (m == 1) ? QSCALE : 1.0f;   // fold attn scale into q

        floatx4 acc[8];
        #pragma unroll
        for (int nt = 0; nt < 8; ++nt) { acc[nt][0]=0.f; acc[nt][1]=0.f; acc[nt][2]=0.f; acc[nt][3]=0.f; }
        #pragma unroll
        for (int nt = 0; nt < 8; ++nt)
            #pragma unroll
            for (int ks = 0; ks < 2; ++ks) {
                half8 bf = *(const half8*)(Wm + (nt * 16 + col) * C_ + ks * 32 + quad * 8);
                acc[nt] = __builtin_amdgcn_mfma_f32_16x16x32_f16(ax[ks], bf, acc[nt], 0, 0, 0);
            }

        if (m < 2) {
            // wave-private scratch: DS ops of one wave execute in order -> no barrier
            f16* S = Sw + wave * 16 * QKS;
            #pragma unroll
            for (int nt = 0; nt < 8; ++nt)
                #pragma unroll
                for (int r = 0; r < 4; ++r)
                    S[(quad * 4 + r) * QKS + nt * 16 + col] = f2h(acc[nt][r] * sc);
            f16* o = (m == 0) ? ko : qo;
            int rw = lane >> 2;
            #pragma unroll
            for (int p = 0; p < 4; ++p) {
                int ck = (lane & 3) + p * 4;
                half8 d = *(const half8*)&S[rw * QKS + ck * 8];
                *(half8*)(o + ((size_t)(b * T_ + t0 + wave * 16 + rw)) * H_ + ck * 8) = d;
            }
        } else {
            __syncthreads();   // all waves' q-scratch reads done; vtl spans whole smem
            #pragma unroll
            for (int nt = 0; nt < 8; ++nt)
                #pragma unroll
                for (int r = 0; r < 4; ++r)
                    vtl[(nt * 16 + col) * VTS + wave * 16 + quad * 4 + r] = f2h(acc[nt][r]);
            __syncthreads();
            // permuted store: source granule gs (t = 8gs..8gs+7) splits into two
            // 8-B halves at positions (G, u4) and (G+1, u4), G = 4*gs2 + 2*gs0,
            // u4 = 4*gs1  (see layout comment above).
            int h  = tid >> 1;
            int sg = (tid & 1) * 32;
            f16* drow = vto + ((size_t)(b * H_ + h)) * T_ + t0;
            const int4* src = (const int4*)&vtl[h * VTS + sg];
            #pragma unroll
            for (int i = 0; i < 4; ++i) {
                int gs = (sg >> 3) + i;
                int G  = ((gs >> 2) << 2) | ((gs & 1) << 1);
                int u4 = ((gs >> 1) & 1) << 2;
                int4 v = src[i];
                *(int2*)(drow + (G + 0) * 8 + u4) = make_int2(v.x, v.y);
                *(int2*)(drow + (G + 1) * 8 + u4) = make_int2(v.z, v.w);
            }
        }
    }
}

// ---------------------------------------------------------------------------
// Flash attention, BK=128 (this round): HALF the barrier rendezvous of the
// BK=64 version (64 vs 128 per block) — measured cycle budget showed ~1/3 of
// chunk time was rendezvous, with DS the top pipe (67%) and its volume fixed
// by the decomposition. Single-buffered K[128][128] + V[2][128][64] = 64 KB
// LDS, 2 blocks/CU. Grid (16 b, 32 q): b -> XCD, K/V L2-resident (24 MB FETCH).
// Per chunk:
//   B1 (K(ci) landed; prior PV's V reads done) -> issue V(ci)
//   QK half0 -> softmax half0 -> QK half1      (V lands under this)
//   B3 (V(ci) landed; all Kl reads done) -> issue K(ci+1)
//   softmax half1 -> PV sp0..3 (single b128 V reads, permuted-vt layout)
// lsum completes in-kernel -> normalize in epilogue, single output pass.
// ---------------------------------------------------------------------------
__global__ __launch_bounds__(256, 2) void attn_kernel(
    const f16* __restrict__ q,
    const f16* __restrict__ k,
    const f16* __restrict__ vt,
    float* __restrict__ out)
{
    __shared__ __align__(16) f16 Kl[128 * 128];     // 32768 B, swizzled granules
    __shared__ __align__(16) f16 Vtl[2][128 * 64];  // 32768 B, [t-half][h][64 t']

    const int tid  = threadIdx.x;
    const int wave = tid >> 6;
    const int lane = tid & 63;
    const int col  = lane & 15;
    const int quad = lane >> 4;
    const int c7   = col & 7;
    const int b    = blockIdx.x;            // XCD = b % 8
    const int q0   = blockIdx.y * BQ;
    const int NC   = T_ / BK;               // 32 chunks

    // staging lane constants
    const int klr = lane >> 4;          // K: row-in-slab 0..3
    const int kph = (lane & 15) & 8;    // K: granule pos high bit
    const int kpl = lane & 7;           // K: granule pos low bits
    const int vrow = lane >> 3;         // V: row-in-call 0..7
    const int vswz = (lane & 7) ^ vrow; // V: swizzled source granule

    // Q fragments (reused NC chunks) — B-operand layout [n=lane&15][k=quad*8+j]
    half8 qf[2][4];
    #pragma unroll
    for (int qt = 0; qt < 2; ++qt) {
        const f16* qrow =
            q + ((size_t)(b * T_ + q0 + wave * 32 + qt * 16 + col)) * H_ + quad * 8;
        #pragma unroll
        for (int ks = 0; ks < 4; ++ks)
            qf[qt][ks] = *(const half8*)(qrow + ks * 32);
    }

    floatx4 o[2][8];   // Ot accum: lane holds q=qt*16+col, h=ht*16+quad*4+r
    #pragma unroll
    for (int qt = 0; qt < 2; ++qt)
        #pragma unroll
        for (int ht = 0; ht < 8; ++ht) { o[qt][ht][0]=0.f; o[qt][ht][1]=0.f; o[qt][ht][2]=0.f; o[qt][ht][3]=0.f; }
    float lsum[2] = {0.f, 0.f};

    // K: 32 slabs (4 rows x 128 d each); 8 calls/wave
    #define ISSUE_K(S0)                                                           \
        do { _Pragma("unroll")                                                    \
            for (int it = 0; it < 8; ++it) {                                      \
                int slab = wave * 8 + it;                                         \
                int r7   = ((slab & 1) * 4 + klr);                                \
                int g    = kph | (kpl ^ r7);                                      \
                async_cp16(k + ((size_t)(b * T_ + (S0) + slab * 4 + klr)) * H_ + g * 8, \
                           (void*)&Kl[slab * 512]);                               \
            }                                                                     \
        } while (0)

    // V: 8 calls/wave = 4 h-groups x 2 t-halves
    #define ISSUE_VT(S0)                                                          \
        do { _Pragma("unroll")                                                    \
            for (int it = 0; it < 4; ++it) {                                      \
                int hbase = wave * 32 + it * 8;                                   \
                _Pragma("unroll")                                                 \
                for (int th = 0; th < 2; ++th)                                    \
                    async_cp16(vt + ((size_t)(b * H_ + hbase + vrow)) * T_ + (S0) + th * 64 + vswz * 8, \
                               (void*)&Vtl[th][hbase * 64]);                      \
            }                                                                     \
        } while (0)

    // QK 32-MFMA cluster + softmax for one 64-k half (kh): fills pf[qt][kh*4+st]
    #define QKHALF(KH)                                                            \
        do {                                                                      \
            half8 kf[4][4];                                                       \
            _Pragma("unroll")                                                     \
            for (int st = 0; st < 4; ++st)                                        \
                _Pragma("unroll")                                                 \
                for (int ks = 0; ks < 4; ++ks) {                                  \
                    int p = ((ks & 2) << 2) | ((((ks & 1) * 4) + quad) ^ c7);     \
                    kf[st][ks] = *(const half8*)&Kl[((KH) * 64 + st * 16 + col) * 128 + p * 8]; \
                }                                                                 \
            floatx4 s[2][4];                                                      \
            __builtin_amdgcn_s_setprio(1);                                        \
            _Pragma("unroll")                                                     \
            for (int st = 0; st < 4; ++st) {                                      \
                s[0][st] = floatx4{0.f, 0.f, 0.f, 0.f};                           \
                s[1][st] = floatx4{0.f, 0.f, 0.f, 0.f};                           \
                _Pragma("unroll")                                                 \
                for (int ks = 0; ks < 4; ++ks) {                                  \
                    s[0][st] = __builtin_amdgcn_mfma_f32_16x16x32_f16(kf[st][ks], qf[0][ks], s[0][st], 0, 0, 0); \
                    s[1][st] = __builtin_amdgcn_mfma_f32_16x16x32_f16(kf[st][ks], qf[1][ks], s[1][st], 0, 0, 0); \
                }                                                                 \
            }                                                                     \
            __builtin_amdgcn_s_setprio(0);                                        \
            _Pragma("unroll")                                                     \
            for (int st = 0; st < 4; ++st)                                        \
                _Pragma("unroll")                                                 \
                for (int qt = 0; qt < 2; ++qt) {                                  \
                    float p0 = fexp2(s[qt][st][0]), p1 = fexp2(s[qt][st][1]);     \
                    float p2 = fexp2(s[qt][st][2]), p3 = fexp2(s[qt][st][3]);     \
                    lsum[qt] += (p0 + p1) + (p2 + p3);                            \
                    pf[qt][(KH) * 4 + st] = __builtin_shufflevector(pkrtz(p0, p1), pkrtz(p2, p3), 0, 1, 2, 3); \
                }                                                                 \
        } while (0)

    // PV cluster for one 32-k tile-pair sp (0..3): V half sp>>1, tile sp&1
    #define PVQUARTER(SP)                                                         \
        do {                                                                      \
            half8 p8[2];                                                          \
            _Pragma("unroll")                                                     \
            for (int qt = 0; qt < 2; ++qt)                                        \
                p8[qt] = __builtin_shufflevector(pf[qt][(SP) * 2], pf[qt][(SP) * 2 + 1], \
                                                 0, 1, 2, 3, 4, 5, 6, 7);         \
            const int gl8 = ((((SP) & 1) * 4 + quad) ^ c7) * 8;                   \
            half8 va[8];                                                          \
            _Pragma("unroll")                                                     \
            for (int ht = 0; ht < 8; ++ht)                                        \
                va[ht] = *(const half8*)&Vtl[(SP) >> 1][(ht * 16 + col) * 64 + gl8]; \
            __builtin_amdgcn_s_setprio(1);                                        \
            _Pragma("unroll")                                                     \
            for (int ht = 0; ht < 8; ++ht) {                                      \
                o[0][ht] = __builtin_amdgcn_mfma_f32_16x16x32_f16(va[ht], p8[0], o[0][ht], 0, 0, 0); \
                o[1][ht] = __builtin_amdgcn_mfma_f32_16x16x32_f16(va[ht], p8[1], o[1][ht], 0, 0, 0); \
            }                                                                     \
            __builtin_amdgcn_s_setprio(0);                                        \
        } while (0)

    ISSUE_K(0);    // prologue: chunk 0 (one-time startup stall)

    for (int ci = 0; ci < NC; ++ci) {
        const int s0c = ci * BK;
        __syncthreads();      // B1: K(ci) landed; prior PV's Vtl reads done
        ISSUE_VT(s0c);        // V(ci); lands under QK0+SM0+QK1 (~2500 cyc)

        half4 pf[2][8];       // P fragments for all 8 k16-tiles
        QKHALF(0);            // kf reads + 32 MFMA + softmax half 0
        QKHALF(1);            // kf reads + 32 MFMA + softmax half 1

        __syncthreads();      // B3: V(ci) landed; all Kl reads done
        if (ci + 1 < NC) ISSUE_K(s0c + BK);   // K(ci+1); lands under PV (~2600 cyc)

        PVQUARTER(0);
        PVQUARTER(1);
        PVQUARTER(2);
        PVQUARTER(3);
    }
    #undef ISSUE_K
    #undef ISSUE_VT
    #undef QKHALF
    #undef PVQUARTER

    // epilogue: reduce lsum across quads, normalize, store final fp32
    #pragma unroll
    for (int qt = 0; qt < 2; ++qt) {
        float l = lsum[qt];
        l += __shfl_xor(l, 16);
        l += __shfl_xor(l, 32);
        float rinv = 1.0f / l;
        int qrow = q0 + wave * 32 + qt * 16 + col;
        float* orow = out + ((size_t)(b * T_ + qrow)) * H_;
        #pragma unroll
        for (int ht = 0; ht < 8; ++ht) {
            float4 st4 = {o[qt][ht][0] * rinv, o[qt][ht][1] * rinv,
                          o[qt][ht][2] * rinv, o[qt][ht][3] * rinv};
            *(float4*)&orow[ht * 16 + quad * 4] = st4;
        }
    }
}

extern "C" void kernel_launch(void* const* d_in, const int* in_sizes, int n_in,
                              void* d_out, int out_size, void* d_ws, size_t ws_size,
                              hipStream_t stream)
{
    const float* x  = (const float*)d_in[0];
    const float* Wk = (const float*)d_in[1];
    const float* Wq = (const float*)d_in[2];
    const float* Wv = (const float*)d_in[3];
    float* out = (float*)d_out;

    const size_t elems = (size_t)B_ * T_ * H_;            // 8.4M elements
    f16* qb  = (f16*)d_ws;                                // f16 q   [B][T][H]    16.8 MB
    f16* kb  = qb + elems;                                // f16 k   [B][T][H]    16.8 MB
    f16* vtb = kb + elems;                                // f16 v^T [B][H][T']   16.8 MB (permuted t)
    f16* wtb = vtb + elems;                               // f16 W^T [3][H][C]    48 KB

    wprep_kernel<<<dim3(3, 16), dim3(256), 0, stream>>>(Wk, Wq, Wv, wtb);
    proj_kernel<<<dim3(B_ * 64), dim3(256), 0, stream>>>(x, wtb, qb, kb, vtb);
    attn_kernel<<<dim3(B_, T_ / BQ), dim3(256), 0, stream>>>(qb, kb, vtb, out);
}

// Round 13
// 230.592 us; speedup vs baseline: 1.0216x; 1.0216x over previous
//
#include <hip/hip_runtime.h>
#include <stdint.h>

#define B_ 16
#define T_ 4096
#define C_ 64
#define H_ 128
#define BQ 128
#define BK 64

typedef _Float16 f16;
typedef __attribute__((ext_vector_type(8))) _Float16 half8;   // 4 VGPRs (16x16x32 A/B)
typedef __attribute__((ext_vector_type(4))) _Float16 half4;   // 2 VGPRs
typedef __attribute__((ext_vector_type(2))) _Float16 half2v;  // 1 VGPR
typedef __attribute__((ext_vector_type(4))) float   floatx4;  // MFMA C/D frag

__device__ __forceinline__ f16 f2h(float f) { return (f16)f; }

__device__ __forceinline__ float fexp2(float x) {
#if __has_builtin(__builtin_amdgcn_exp2f)
    return __builtin_amdgcn_exp2f(x);
#else
    return exp2f(x);
#endif
}

// packed f32x2 -> f16x2 (single v_cvt_pkrtz_f16_f32)
__device__ __forceinline__ half2v pkrtz(float a, float b) {
    return __builtin_bit_cast(half2v, __builtin_amdgcn_cvt_pkrtz(a, b));
}

// async global->LDS, 16 B per lane, dest = wave-uniform base + lane*16
__device__ __forceinline__ void async_cp16(const void* g, void* l) {
    __builtin_amdgcn_global_load_lds(
        (const __attribute__((address_space(1))) unsigned int*)g,
        (__attribute__((address_space(3))) unsigned int*)l, 16, 0, 0);
}

// q is pre-scaled by scale*log2(e) at projection time (attn does exp2(S) raw)
#define QSCALE 0.18033688011112042f   // 0.125 * log2(e)

// ---------------------------------------------------------------------------
// W prep: Wk/Wq/Wv fp32 [C][H] -> f16 W^T [m][H][C], done ONCE.
// Grid (3 m, 16 h-groups) = 48 blocks.
// ---------------------------------------------------------------------------
__global__ __launch_bounds__(256) void wprep_kernel(
    const float* __restrict__ Wk, const float* __restrict__ Wq,
    const float* __restrict__ Wv, f16* __restrict__ wt)
{
    const int m  = blockIdx.x;
    const int hg = blockIdx.y;
    const float* W = (m == 0) ? Wk : (m == 1) ? Wq : Wv;
    f16* o = wt + m * (C_ * H_);
    #pragma unroll
    for (int it = 0; it < 2; ++it) {
        int idx = hg * 512 + it * 256 + threadIdx.x;  // idx = h*64 + c
        int h = idx >> 6, c = idx & 63;
        o[idx] = f2h(W[c * H_ + h]);                  // strided 4B reads, L2-resident
    }
}

// ---------------------------------------------------------------------------
// MFMA projections: q,k -> f16 [B][T][H]; v -> PRE-FRAGMENTED vt2:
//   vt2[ ((b*64 + tc)*8 + g) * 1024 + h * 8 .. +8 ]  (f16 units)
// holds the 8 f16 A-operand k-values for PV tile-pair sp = g>>2, quad = g&3,
// chunk tc, V-row h: klo = sp*32 + quad*4 (4 values) then klo+16 (4 values) —
// bit-identical content to the old permuted-vt granule, but now CONSECUTIVE
// h are CONSECUTIVE 16-B granules in global, so attn's V load is a fully
// coalesced global_load_dwordx4 (round 10's scatter problem eliminated).
// q (m==1) is multiplied by QSCALE before the f16 store.
// ---------------------------------------------------------------------------
#define QKS 132   // q/k scratch stride (f16)
#define VTS 72    // vt scratch stride (f16)

__global__ __launch_bounds__(256) void proj_kernel(
    const float* __restrict__ x, const f16* __restrict__ wt,
    f16* __restrict__ qo, f16* __restrict__ ko, f16* __restrict__ vto)
{
    __shared__ __align__(16) char smem[20480];
    f16* Sw  = (f16*)smem;                          // per-wave [16][QKS] transpose scratch
    f16* vtl = (f16*)smem;                          // [128 h][VTS]  18432 B (aliases Sw)

    const int tid  = threadIdx.x;
    const int wave = tid >> 6;
    const int lane = tid & 63;
    const int col  = lane & 15;
    const int quad = lane >> 4;
    const int b    = blockIdx.x >> 6;
    const int tc   = blockIdx.x & 63;
    const int t0   = tc * 64;

    // A-fragments: x rows t0+wave*16+col, K=64 in 2 ks-steps (fp32 -> f16)
    half8 ax[2];
    {
        const float* xr = x + ((size_t)(b * T_ + t0 + wave * 16 + col)) * C_ + quad * 8;
        #pragma unroll
        for (int ks = 0; ks < 2; ++ks) {
            float4 a0 = *(const float4*)(xr + ks * 32);
            float4 a1 = *(const float4*)(xr + ks * 32 + 4);
            ax[ks] = half8{f2h(a0.x), f2h(a0.y), f2h(a0.z), f2h(a0.w),
                           f2h(a1.x), f2h(a1.y), f2h(a1.z), f2h(a1.w)};
        }
    }

    #pragma unroll
    for (int m = 0; m < 3; ++m) {
        const f16* Wm = wt + m * (C_ * H_);
        const float sc = (m == 1) ? QSCALE : 1.0f;   // fold attn scale into q

        floatx4 acc[8];
        #pragma unroll
        for (int nt = 0; nt < 8; ++nt) { acc[nt][0]=0.f; acc[nt][1]=0.f; acc[nt][2]=0.f; acc[nt][3]=0.f; }
        #pragma unroll
        for (int nt = 0; nt < 8; ++nt)
            #pragma unroll
            for (int ks = 0; ks < 2; ++ks) {
                half8 bf = *(const half8*)(Wm + (nt * 16 + col) * C_ + ks * 32 + quad * 8);
                acc[nt] = __builtin_amdgcn_mfma_f32_16x16x32_f16(ax[ks], bf, acc[nt], 0, 0, 0);
            }

        if (m < 2) {
            // wave-private scratch: DS ops of one wave execute in order -> no barrier
            f16* S = Sw + wave * 16 * QKS;
            #pragma unroll
            for (int nt = 0; nt < 8; ++nt)
                #pragma unroll
                for (int r = 0; r < 4; ++r)
                    S[(quad * 4 + r) * QKS + nt * 16 + col] = f2h(acc[nt][r] * sc);
            f16* o = (m == 0) ? ko : qo;
            int rw = lane >> 2;
            #pragma unroll
            for (int p = 0; p < 4; ++p) {
                int ck = (lane & 3) + p * 4;
                half8 d = *(const half8*)&S[rw * QKS + ck * 8];
                *(half8*)(o + ((size_t)(b * T_ + t0 + wave * 16 + rw)) * H_ + ck * 8) = d;
            }
        } else {
            __syncthreads();   // all waves' q-scratch reads done; vtl spans whole smem
            #pragma unroll
            for (int nt = 0; nt < 8; ++nt)
                #pragma unroll
                for (int r = 0; r < 4; ++r)
                    vtl[(nt * 16 + col) * VTS + wave * 16 + quad * 4 + r] = f2h(acc[nt][r]);
            __syncthreads();
            // vt2 fragment store: thread t -> h = t&127, g-half = t>>7;
            // 4 passes cover g = p*2 + ghalf. Per granule: two b64 scratch
            // reads (klo, klo+16) -> one coalesced b128 global store
            // (lanes = consecutive h -> dense 2 KB per instruction).
            int h  = tid & 127;
            int gh = tid >> 7;
            f16* dbase = vto + ((size_t)(b * 64 + tc) * 8) * 1024;
            const f16* src = &vtl[h * VTS];
            #pragma unroll
            for (int p = 0; p < 4; ++p) {
                int g   = p * 2 + gh;
                int klo = (g >> 2) * 32 + (g & 3) * 4;
                half4 lo = *(const half4*)(src + klo);
                half4 hi = *(const half4*)(src + klo + 16);
                half8 gr = __builtin_shufflevector(lo, hi, 0, 1, 2, 3, 4, 5, 6, 7);
                *(half8*)(dbase + ((size_t)g * 128 + h) * 8) = gr;
            }
        }
    }
}

// ---------------------------------------------------------------------------
// Flash attention. Grid (16 b, 32 q): x = b -> all 32 q-blocks of a batch on
// one XCD, K/V served from its L2 (FETCH ~25 MB, round 9).
// DS-pipe diet v2: V comes from global as PRE-FRAGMENTED vt2 granules —
// coalesced b128 loads (consecutive lanes -> consecutive 16 B), L1/L2-hot,
// content bit-identical to the old swizzled LDS read. DS per chunk halves to
// K-only (was the top pipe at ~58%). K stays LDS-staged (4x wave dedupe),
// double-buffered, ONE barrier per chunk; chunk loop unrolled x2 for
// compile-time buffer index. va0 issued under QK cover, va1 under softmax.
// Round-9 phase order otherwise: unified 32-MFMA QK -> softmax -> PV.
// lsum completes in-kernel -> normalize in epilogue, single output pass.
// ---------------------------------------------------------------------------
__global__ __launch_bounds__(256, 2) void attn_kernel(
    const f16* __restrict__ q,
    const f16* __restrict__ k,
    const f16* __restrict__ vt2,
    float* __restrict__ out)
{
    __shared__ __align__(16) f16 Kl[2][64 * 128];   // 32768 B, K dbuf, swizzled

    const int tid  = threadIdx.x;
    const int wave = tid >> 6;
    const int lane = tid & 63;
    const int col  = lane & 15;
    const int quad = lane >> 4;
    const int c7   = col & 7;
    const int b    = blockIdx.x;            // XCD = b % 8
    const int q0   = blockIdx.y * BQ;
    const int NC   = T_ / BK;

    // staging lane constants (K only)
    const int klr = lane >> 4;          // K: row-in-slab 0..3
    const int kph = (lane & 15) & 8;    // K: granule pos high bit
    const int kpl = lane & 7;           // K: granule pos low bits

    // V fragment base: lane reads granule (g = sp*4+quad, h = ht*16+col)
    const f16* vlane = vt2 + ((size_t)(b * 64) * 8 + quad) * 1024 + col * 8;

    // Q fragments (reused NC chunks) — B-operand layout [n=lane&15][k=quad*8+j]
    half8 qf[2][4];
    #pragma unroll
    for (int qt = 0; qt < 2; ++qt) {
        const f16* qrow =
            q + ((size_t)(b * T_ + q0 + wave * 32 + qt * 16 + col)) * H_ + quad * 8;
        #pragma unroll
        for (int ks = 0; ks < 4; ++ks)
            qf[qt][ks] = *(const half8*)(qrow + ks * 32);
    }

    floatx4 o[2][8];   // Ot accum: lane holds q=qt*16+col, h=ht*16+quad*4+r
    #pragma unroll
    for (int qt = 0; qt < 2; ++qt)
        #pragma unroll
        for (int ht = 0; ht < 8; ++ht) { o[qt][ht][0]=0.f; o[qt][ht][1]=0.f; o[qt][ht][2]=0.f; o[qt][ht][3]=0.f; }
    float lsum[2] = {0.f, 0.f};

    #define ISSUE_K(S0, BUF)                                                      \
        do { _Pragma("unroll")                                                    \
            for (int it = 0; it < 4; ++it) {                                      \
                int slab = wave * 4 + it;                                         \
                int r7   = ((slab & 1) * 4 + klr);                                \
                int g    = kph | (kpl ^ r7);                                      \
                async_cp16(k + ((size_t)(b * T_ + (S0) + slab * 4 + klr)) * H_ + g * 8, \
                           (void*)&Kl[BUF][slab * 512]);                          \
            }                                                                     \
        } while (0)

    ISSUE_K(0, 0);     // prologue: chunk 0 (one-time startup stall)

    for (int ci2 = 0; ci2 < NC; ci2 += 2) {
        #pragma unroll
        for (int sub = 0; sub < 2; ++sub) {
            const int ci  = ci2 + sub;
            const int buf = sub;                 // compile-time LDS buffer index
            const int s0c = ci * BK;
            // ONE barrier per chunk: implicit vmcnt(0) drains K(ci) (issued a
            // full chunk ago); prior chunk's reads of Kl[buf] are done.
            __syncthreads();
            if (ci + 1 < NC) ISSUE_K(s0c + BK, buf ^ 1);   // full-chunk cover

            const f16* vchunk = vlane + (size_t)ci * 8192;

            // ---- va0: V tile-pair 0 fragments, coalesced b128 from global;
            //      completes under the QK cluster
            half8 va0[8];
            #pragma unroll
            for (int ht = 0; ht < 8; ++ht)
                va0[ht] = *(const half8*)(vchunk + ht * 128);

            // ---- K fragment preload: 16x ds_read_b128, addresses loop-invariant
            half8 kf[4][4];
            #pragma unroll
            for (int st = 0; st < 4; ++st)
                #pragma unroll
                for (int ks = 0; ks < 4; ++ks) {
                    int p = ((ks & 2) << 2) | ((((ks & 1) * 4) + quad) ^ c7);
                    kf[st][ks] = *(const half8*)&Kl[buf][(st * 16 + col) * 128 + p * 8];
                }

            // ---- QK: pure-register 32-MFMA cluster (unified)
            floatx4 s[2][4];
            __builtin_amdgcn_s_setprio(1);
            #pragma unroll
            for (int st = 0; st < 4; ++st) {
                s[0][st] = floatx4{0.f, 0.f, 0.f, 0.f};
                s[1][st] = floatx4{0.f, 0.f, 0.f, 0.f};
                #pragma unroll
                for (int ks = 0; ks < 4; ++ks) {
                    s[0][st] = __builtin_amdgcn_mfma_f32_16x16x32_f16(kf[st][ks], qf[0][ks], s[0][st], 0, 0, 0);
                    s[1][st] = __builtin_amdgcn_mfma_f32_16x16x32_f16(kf[st][ks], qf[1][ks], s[1][st], 0, 0, 0);
                }
            }
            __builtin_amdgcn_s_setprio(0);

            // ---- va1: V tile-pair 1 fragments; completes under softmax
            half8 va1[8];
            #pragma unroll
            for (int ht = 0; ht < 8; ++ht)
                va1[ht] = *(const half8*)(vchunk + 4096 + ht * 128);

            // ---- softmax: single VALU phase (q pre-scaled by scale*log2e)
            half4 pf[2][4];
            #pragma unroll
            for (int st = 0; st < 4; ++st)
                #pragma unroll
                for (int qt = 0; qt < 2; ++qt) {
                    float p0 = fexp2(s[qt][st][0]), p1 = fexp2(s[qt][st][1]);
                    float p2 = fexp2(s[qt][st][2]), p3 = fexp2(s[qt][st][3]);
                    lsum[qt] += (p0 + p1) + (p2 + p3);
                    pf[qt][st] = __builtin_shufflevector(pkrtz(p0, p1), pkrtz(p2, p3), 0, 1, 2, 3);
                }

            // ---- PV: A-operand = the lane's own coalesced V fragments
            #pragma unroll
            for (int sp32 = 0; sp32 < 2; ++sp32) {
                half8 p8[2];
                #pragma unroll
                for (int qt = 0; qt < 2; ++qt)
                    p8[qt] = __builtin_shufflevector(pf[qt][sp32 * 2], pf[qt][sp32 * 2 + 1],
                                                     0, 1, 2, 3, 4, 5, 6, 7);
                __builtin_amdgcn_s_setprio(1);
                #pragma unroll
                for (int ht = 0; ht < 8; ++ht) {
                    half8 va = sp32 ? va1[ht] : va0[ht];
                    o[0][ht] = __builtin_amdgcn_mfma_f32_16x16x32_f16(va, p8[0], o[0][ht], 0, 0, 0);
                    o[1][ht] = __builtin_amdgcn_mfma_f32_16x16x32_f16(va, p8[1], o[1][ht], 0, 0, 0);
                }
                __builtin_amdgcn_s_setprio(0);
            }
        }
    }
    #undef ISSUE_K

    // epilogue: reduce lsum across quads, normalize, store final fp32
    #pragma unroll
    for (int qt = 0; qt < 2; ++qt) {
        float l = lsum[qt];
        l += __shfl_xor(l, 16);
        l += __shfl_xor(l, 32);
        float rinv = 1.0f / l;
        int qrow = q0 + wave * 32 + qt * 16 + col;
        float* orow = out + ((size_t)(b * T_ + qrow)) * H_;
        #pragma unroll
        for (int ht = 0; ht < 8; ++ht) {
            float4 st4 = {o[qt][ht][0] * rinv, o[qt][ht][1] * rinv,
                          o[qt][ht][2] * rinv, o[qt][ht][3] * rinv};
            *(float4*)&orow[ht * 16 + quad * 4] = st4;
        }
    }
}

extern "C" void kernel_launch(void* const* d_in, const int* in_sizes, int n_in,
                              void* d_out, int out_size, void* d_ws, size_t ws_size,
                              hipStream_t stream)
{
    const float* x  = (const float*)d_in[0];
    const float* Wk = (const float*)d_in[1];
    const float* Wq = (const float*)d_in[2];
    const float* Wv = (const float*)d_in[3];
    float* out = (float*)d_out;

    const size_t elems = (size_t)B_ * T_ * H_;            // 8.4M elements
    f16* qb  = (f16*)d_ws;                                // f16 q   [B][T][H]        16.8 MB
    f16* kb  = qb + elems;                                // f16 k   [B][T][H]        16.8 MB
    f16* vtb = kb + elems;                                // f16 vt2 fragments        16.8 MB
    f16* wtb = vtb + elems;                               // f16 W^T [3][H][C]        48 KB

    wprep_kernel<<<dim3(3, 16), dim3(256), 0, stream>>>(Wk, Wq, Wv, wtb);
    proj_kernel<<<dim3(B_ * 64), dim3(256), 0, stream>>>(x, wtb, qb, kb, vtb);
    attn_kernel<<<dim3(B_, T_ / BQ), dim3(256), 0, stream>>>(qb, kb, vtb, out);
}